// Round 8
// baseline (712.990 us; speedup 1.0000x reference)
//
#include <hip/hip_runtime.h>
#include <hip/hip_bf16.h>

#define NN 16384
#define NE 65536
#define NB 512          // mega-kernel grid

typedef __attribute__((ext_vector_type(8))) short short8;
typedef __attribute__((ext_vector_type(4))) float f32x4;

using bf16 = __hip_bfloat16;

__device__ __forceinline__ float b2f(bf16 v){ return __bfloat162float(v); }
__device__ __forceinline__ bf16 f2b(float v){ return __float2bfloat16(v); }

struct MA {
    const float *x, *y, *rel, *a;
    const int *send, *recv;
    const float *W[4], *P[4];
    const float *bb[4], *bs[4], *bo[4], *bm[4], *bv[4];
    float* g;                 // [4][NE][16]
    unsigned *curs, *csr;
    unsigned *bcnt, *bgen;    // grid barrier state (memset to 0)
    bf16 *h1, *xo, *h3, *Bp, *xyc;
    float* outp;
};

// ---------------- hand-rolled grid barrier: per-BLOCK arrival ----------------
__device__ __forceinline__ void gridbar(unsigned* cnt, unsigned* gen, unsigned nb){
    __syncthreads();
    if(threadIdx.x == 0){
        __threadfence();   // release all prior writes (agent scope)
        unsigned g0 = __hip_atomic_load(gen, __ATOMIC_RELAXED, __HIP_MEMORY_SCOPE_AGENT);
        unsigned a  = __hip_atomic_fetch_add(cnt, 1u, __ATOMIC_ACQ_REL, __HIP_MEMORY_SCOPE_AGENT);
        if(a == nb - 1u){
            __hip_atomic_store(cnt, 0u, __ATOMIC_RELAXED, __HIP_MEMORY_SCOPE_AGENT);
            __hip_atomic_fetch_add(gen, 1u, __ATOMIC_RELEASE, __HIP_MEMORY_SCOPE_AGENT);
        } else {
            while(__hip_atomic_load(gen, __ATOMIC_ACQUIRE, __HIP_MEMORY_SCOPE_AGENT) == g0)
                __builtin_amdgcn_s_sleep(8);
        }
        __threadfence();   // acquire side
    }
    __syncthreads();
}

// ---------------- phase 1: countfill | tap softmax | W pack | xyc ----------
__device__ __forceinline__ void ph1(const MA& A){
    int gtid = blockIdx.x*1024 + threadIdx.x;    // [0, 524288)
    if(gtid < NE){
        int e = gtid;
        int rv = A.recv[e];
        unsigned pos = atomicAdd(&A.curs[rv], 1u);
        if(pos < 32u) A.csr[(unsigned)rv*32u + pos] = ((unsigned)e << 14) | (unsigned)A.send[e];
        return;
    }
    if(gtid < NE + 4*NE){
        int task = gtid - NE;
        int e = task & (NE-1), c = task >> 16;
        float r0 = A.rel[e*3+0], r1 = A.rel[e*3+1], r2 = A.rel[e*3+2];
        float av = A.a[e];
        const float* P = A.P[c];
        float lg[16]; float mx = -1e30f;
        #pragma unroll
        for(int k=0;k<16;k++){
            float v = r0*P[k] + r1*P[16+k] + r2*P[32+k];
            lg[k] = v; mx = fmaxf(mx, v);
        }
        float ssum = 0.f;
        #pragma unroll
        for(int k=0;k<16;k++){ lg[k] = __expf(lg[k]-mx); ssum += lg[k]; }
        float inv = av/ssum;
        float* go = A.g + ((size_t)c*NE + e)*16;
        #pragma unroll
        for(int j=0;j<4;j++){
            ((float4*)go)[j] = make_float4(lg[j*4]*inv, lg[j*4+1]*inv,
                                           lg[j*4+2]*inv, lg[j*4+3]*inv);
        }
        return;
    }
    if(gtid < 327680 + 20480){
        int t = gtid - 327680;
        const float* W; int Cout; int base; int tl;
        if(t < 8192)      { W=A.W[0]; Cout=64; base=0;     tl=t; }
        else if(t < 12288){ W=A.W[1]; Cout=32; base=8192;  tl=t-8192; }
        else if(t < 16384){ W=A.W[2]; Cout=64; base=12288; tl=t-12288; }
        else              { W=A.W[3]; Cout=32; base=16384; tl=t-16384; }
        int l  = tl & 63;
        int NCT = Cout >> 4;
        int ct = (tl >> 6) % NCT;
        int ks = (tl >> 6) / NCT;
        int col = ct*16 + (l & 15);
        int k0  = ks*32 + ((l >> 4) & 3)*8;
        short8 v;
        #pragma unroll
        for(int j=0;j<8;j++){
            bf16 h = f2b(W[(size_t)(k0+j)*Cout + col]);
            v[j] = (short)*(unsigned short*)&h;
        }
        ((short8*)A.Bp)[base + tl] = v;
        return;
    }
    if(gtid < 348160 + 32768){
        int t = gtid - 348160;
        int n = t >> 1, half = t & 1;
        const float* src = half ? (A.y + n*32) : (A.x + n*32);
        bf16* dst = A.xyc + (size_t)n*64 + half*32;
        #pragma unroll
        for(int j=0;j<4;j++){
            float4 v0 = ((const float4*)src)[2*j];
            float4 v1 = ((const float4*)src)[2*j+1];
            short8 o; bf16 h;
            h = f2b(v0.x); o[0]=(short)*(unsigned short*)&h;
            h = f2b(v0.y); o[1]=(short)*(unsigned short*)&h;
            h = f2b(v0.z); o[2]=(short)*(unsigned short*)&h;
            h = f2b(v0.w); o[3]=(short)*(unsigned short*)&h;
            h = f2b(v1.x); o[4]=(short)*(unsigned short*)&h;
            h = f2b(v1.y); o[5]=(short)*(unsigned short*)&h;
            h = f2b(v1.z); o[6]=(short)*(unsigned short*)&h;
            h = f2b(v1.w); o[7]=(short)*(unsigned short*)&h;
            ((short8*)dst)[j] = o;
        }
    }
}

// ---------------- fused conv phase: 2 tiles, 1 node/wave, no early returns --
template<int CIN, int NCT, int MODE, typename OT>
__device__ __forceinline__ void conv_phase(
    char* sT,
    const bf16* __restrict__ fAb, const float* __restrict__ g,
    const unsigned* __restrict__ csr, const unsigned* __restrict__ curs,
    const bf16* __restrict__ Bp, const float* __restrict__ bias,
    const float* __restrict__ bns, const float* __restrict__ bno,
    const float* __restrict__ bnm, const float* __restrict__ bnv,
    const float* __restrict__ x, const float* __restrict__ y,
    OT* __restrict__ out)
{
    constexpr int KD   = CIN*16;
    constexpr int ROWB = KD*2;
    int wv = threadIdx.x >> 6, lane = threadIdx.x & 63;
    const int i     = (CIN==64) ? lane : (lane & 31);
    const int kbase = (CIN==64) ? 0 : ((lane >> 5) * 8);
    constexpr int KPL = (CIN==64) ? 16 : 8;

    for(int tile=0; tile<2; tile++){
        int nbase = (tile*NB + blockIdx.x)*16;
        int node  = nbase + wv;

        // ---------- aggregation ----------
        const unsigned* crow = csr + (unsigned)node*32u;
        unsigned cnt = curs[node]; if(cnt > 32u) cnt = 32u;
        uint4 c0 = ((const uint4*)crow)[0];
        uint4 c1 = ((const uint4*)crow)[1];
        unsigned uu[8] = {c0.x,c0.y,c0.z,c0.w, c1.x,c1.y,c1.z,c1.w};

        float acc[KPL];
        #pragma unroll
        for(int r=0;r<KPL;r++) acc[r] = 0.f;

        auto edge = [&](unsigned u){
            int sid = (int)(u & 16383u);
            int eid = (int)(u >> 14);
            float fe = b2f(fAb[sid*CIN + i]);
            const float4* gp = (const float4*)&g[(size_t)eid*16 + kbase];
            if(CIN==64){
                float4 g0=gp[0], g1=gp[1], g2=gp[2], g3=gp[3];
                acc[0]  += g0.x*fe; acc[1]  += g0.y*fe; acc[2]  += g0.z*fe; acc[3]  += g0.w*fe;
                acc[4]  += g1.x*fe; acc[5]  += g1.y*fe; acc[6]  += g1.z*fe; acc[7]  += g1.w*fe;
                acc[8]  += g2.x*fe; acc[9]  += g2.y*fe; acc[10] += g2.z*fe; acc[11] += g2.w*fe;
                acc[12] += g3.x*fe; acc[13] += g3.y*fe; acc[14] += g3.z*fe; acc[15] += g3.w*fe;
            } else {
                float4 g0=gp[0], g1=gp[1];
                acc[0] += g0.x*fe; acc[1] += g0.y*fe; acc[2] += g0.z*fe; acc[3] += g0.w*fe;
                acc[4] += g1.x*fe; acc[5] += g1.y*fe; acc[6] += g1.z*fe; acc[7] += g1.w*fe;
            }
        };
        #pragma unroll
        for(int j=0;j<8;j++){
            if((unsigned)j < cnt) edge(uu[j]);
        }
        for(unsigned j=8; j<cnt; j++) edge(crow[j]);

        // ---------- LDS write (swizzled) ----------
        unsigned xo_ = (unsigned)((wv & 7) << 4);
        if(CIN==64){
            #pragma unroll
            for(int k=0;k<16;k++){
                unsigned byte = (unsigned)wv*ROWB + ((((unsigned)(k*64 + lane))*2u) ^ xo_);
                *(bf16*)(sT + byte) = f2b(acc[k]);
            }
        } else {
            #pragma unroll
            for(int r=0;r<8;r++){
                unsigned byte = (unsigned)wv*ROWB + ((((unsigned)((kbase+r)*32 + i))*2u) ^ xo_);
                *(bf16*)(sT + byte) = f2b(acc[r]);
            }
        }
        __syncthreads();

        // ---------- GEMM + epilogue (waves 0..NCT-1) ----------
        if(wv < NCT){
            int r = lane & 15, h = lane >> 4;
            int c = wv;
            const short8* Bp8 = (const short8*)Bp;
            f32x4 acc4 = (f32x4){0.f,0.f,0.f,0.f};
            unsigned xr = (unsigned)((r & 7) << 4);
            #pragma unroll 8
            for(int ks=0; ks<KD/32; ks++){
                unsigned ab = (unsigned)r*ROWB + (((unsigned)(ks*64 + h*16)) ^ xr);
                short8 af  = *(const short8*)(sT + ab);
                short8 bfr = Bp8[(ks*NCT + c)*64 + lane];
                acc4 = __builtin_amdgcn_mfma_f32_16x16x32_bf16(af, bfr, acc4, 0, 0, 0);
            }
            const int Cout = NCT*16;
            int col = c*16 + r;
            float inv = rsqrtf(bnv[col] + 1e-5f);
            float al  = bns[col] * inv;
            float be  = al*(bias[col] - bnm[col]) + bno[col];
            #pragma unroll
            for(int j=0;j<4;j++){
                int rr = nbase + h*4 + j;
                float v = al*acc4[j] + be;
                if(MODE==0){
                    out[(size_t)rr*Cout + col] = (OT)fmaxf(v, 0.f);
                } else {
                    float wei = 1.f/(1.f + __expf(-v));
                    float xv = x[rr*32 + col];
                    float yv = y[rr*32 + col];
                    out[(size_t)rr*32 + col] = (OT)(2.f*xv*wei + 2.f*yv*(1.f - wei));
                }
            }
        }
        __syncthreads();
    }
}

__device__ __forceinline__ void cv1(const MA& A, char* sT){
    conv_phase<64,4,0,bf16>(sT, A.xyc, A.g,                  A.csr, A.curs,
        A.Bp,                  A.bb[0],A.bs[0],A.bo[0],A.bm[0],A.bv[0], nullptr,nullptr, A.h1);
}
__device__ __forceinline__ void cv2(const MA& A, char* sT){
    conv_phase<64,2,1,bf16>(sT, A.h1, A.g + (size_t)1*NE*16, A.csr, A.curs,
        A.Bp + (size_t)8192*8, A.bb[1],A.bs[1],A.bo[1],A.bm[1],A.bv[1], A.x,A.y, A.xo);
}
__device__ __forceinline__ void cv3(const MA& A, char* sT){
    conv_phase<32,4,0,bf16>(sT, A.xo, A.g + (size_t)2*NE*16, A.csr, A.curs,
        A.Bp + (size_t)12288*8,A.bb[2],A.bs[2],A.bo[2],A.bm[2],A.bv[2], nullptr,nullptr, A.h3);
}
__device__ __forceinline__ void cv4(const MA& A, char* sT){
    conv_phase<64,2,1,float>(sT, A.h3, A.g + (size_t)3*NE*16, A.csr, A.curs,
        A.Bp + (size_t)16384*8,A.bb[3],A.bs[3],A.bo[3],A.bm[3],A.bv[3], A.x,A.y, A.outp);
}

// ---------------- mega kernel: 2 dispatches total (memset + this) ----------
__global__ __launch_bounds__(1024, 8) void k_mega(MA A){
    __shared__ __align__(16) char sT[32768];
    ph1(A);
    gridbar(A.bcnt, A.bgen, NB);
    cv1(A, sT);
    gridbar(A.bcnt, A.bgen, NB);
    cv2(A, sT);
    gridbar(A.bcnt, A.bgen, NB);
    cv3(A, sT);
    gridbar(A.bcnt, A.bgen, NB);
    cv4(A, sT);
}

// ---------------- plain fallbacks ----------------
__global__ __launch_bounds__(1024, 8) void k_ph1(MA A){ ph1(A); }
__global__ __launch_bounds__(1024, 8) void k_cv1(MA A){ __shared__ __align__(16) char sT[32768]; cv1(A, sT); }
__global__ __launch_bounds__(1024, 8) void k_cv2(MA A){ __shared__ __align__(16) char sT[32768]; cv2(A, sT); }
__global__ __launch_bounds__(1024, 8) void k_cv3(MA A){ __shared__ __align__(16) char sT[32768]; cv3(A, sT); }
__global__ __launch_bounds__(1024, 8) void k_cv4(MA A){ __shared__ __align__(16) char sT[32768]; cv4(A, sT); }

// ---------------- launch ----------------
extern "C" void kernel_launch(void* const* d_in, const int* in_sizes, int n_in,
                              void* d_out, int out_size, void* d_ws, size_t ws_size,
                              hipStream_t stream){
    MA A;
    A.x    = (const float*)d_in[0];
    A.y    = (const float*)d_in[1];
    A.send = (const int*)d_in[2];
    A.recv = (const int*)d_in[3];
    A.rel  = (const float*)d_in[4];
    A.a    = (const float*)d_in[5];
    for(int i=0;i<4;i++){
        int base = 6 + i*7;
        A.W[i]  = (const float*)d_in[base+0];
        A.P[i]  = (const float*)d_in[base+1];
        A.bb[i] = (const float*)d_in[base+2];
        A.bs[i] = (const float*)d_in[base+3];
        A.bo[i] = (const float*)d_in[base+4];
        A.bm[i] = (const float*)d_in[base+5];
        A.bv[i] = (const float*)d_in[base+6];
    }
    char* w = (char*)d_ws;
    A.g    = (float*)(w);                      // 16,777,216 B
    A.curs = (unsigned*)(w + 16777216);        //     65,536 B
    A.bcnt = (unsigned*)(w + 16842752);        //          4 B
    A.bgen = (unsigned*)(w + 16842816);        //          4 B (own 64B line)
    A.csr  = (unsigned*)(w + 16842880);        //  2,097,152 B
    A.h1   = (bf16*)(w + 18940032);            //  2,097,152 B
    A.xo   = (bf16*)(w + 21037184);            //  1,048,576 B
    A.h3   = (bf16*)(w + 22085760);            //  2,097,152 B
    A.Bp   = (bf16*)(w + 24182912);            //    327,680 B
    A.xyc  = (bf16*)(w + 24510592);            //  2,097,152 B
    A.outp = (float*)d_out;

    // zero curs + barrier state in one node
    hipMemsetAsync(w + 16777216, 0, 65536 + 128, stream);

    void* kp[1] = { (void*)&A };
    hipError_t err = hipLaunchCooperativeKernel((const void*)k_mega,
                                                dim3(NB), dim3(1024), kp, 0, stream);
    if(err != hipSuccess){
        (void)hipGetLastError();
        k_ph1<<<NB, 1024, 0, stream>>>(A);
        k_cv1<<<NB, 1024, 0, stream>>>(A);
        k_cv2<<<NB, 1024, 0, stream>>>(A);
        k_cv3<<<NB, 1024, 0, stream>>>(A);
        k_cv4<<<NB, 1024, 0, stream>>>(A);
    }
}

// Round 9
// 173.130 us; speedup vs baseline: 4.1182x; 4.1182x over previous
//
#include <hip/hip_runtime.h>
#include <hip/hip_bf16.h>

#define NN 16384
#define NE 65536
#define NB 512          // persistent conv grid (16 leaves x 32)

typedef __attribute__((ext_vector_type(8))) short short8;
typedef __attribute__((ext_vector_type(4))) float f32x4;

using bf16 = __hip_bfloat16;

__device__ __forceinline__ float b2f(bf16 v){ return __bfloat162float(v); }
__device__ __forceinline__ bf16 f2b(float v){ return __float2bfloat16(v); }
__device__ __forceinline__ unsigned bfbits(float v){
    bf16 h = f2b(v);
    return (unsigned)*(unsigned short*)&h;
}
__device__ __forceinline__ unsigned cohLoadU32(const unsigned* p){
    return __hip_atomic_load(p, __ATOMIC_RELAXED, __HIP_MEMORY_SCOPE_AGENT);
}
__device__ __forceinline__ void cohStoreU32(unsigned* p, unsigned v){
    __hip_atomic_store(p, v, __ATOMIC_RELAXED, __HIP_MEMORY_SCOPE_AGENT);
}

struct MA {
    const float *x, *y, *rel, *a;
    const int *send, *recv;
    const float *W[4], *P[4];
    const float *bb[4], *bs[4], *bo[4], *bm[4], *bv[4];
    float* g;                    // [4][NE][16]
    unsigned *curs, *csr, *bar;  // bar: root@0, leaf k @ 64*(1+k), gen @ 64*17
    unsigned *h1u, *xou, *h3u;   // coherent intermediates, 2 bf16 / uint
    bf16 *Bp, *xyc;
    float* outp;
};

// ---------------- fenceless grid barrier: 2-level relaxed counters ----------
__device__ __forceinline__ void lightbar(unsigned* bar){
    __syncthreads();   // drains each wave's vmcnt -> coherent stores complete
    if(threadIdx.x == 0){
        unsigned* gen  = bar + 64*17;
        unsigned g0 = __hip_atomic_load(gen, __ATOMIC_RELAXED, __HIP_MEMORY_SCOPE_AGENT);
        unsigned* leaf = bar + 64*(1 + (blockIdx.x & 15));
        unsigned a = __hip_atomic_fetch_add(leaf, 1u, __ATOMIC_RELAXED, __HIP_MEMORY_SCOPE_AGENT);
        bool done = false;
        if(a == (NB/16 - 1u)){
            __hip_atomic_store(leaf, 0u, __ATOMIC_RELAXED, __HIP_MEMORY_SCOPE_AGENT);
            unsigned rr = __hip_atomic_fetch_add(bar, 1u, __ATOMIC_RELAXED, __HIP_MEMORY_SCOPE_AGENT);
            if(rr == 15u){
                __hip_atomic_store(bar, 0u, __ATOMIC_RELAXED, __HIP_MEMORY_SCOPE_AGENT);
                __hip_atomic_fetch_add(gen, 1u, __ATOMIC_RELAXED, __HIP_MEMORY_SCOPE_AGENT);
                done = true;
            }
        }
        if(!done){
            while(__hip_atomic_load(gen, __ATOMIC_RELAXED, __HIP_MEMORY_SCOPE_AGENT) == g0)
                __builtin_amdgcn_s_sleep(32);
        }
    }
    __syncthreads();
}

// ================= k_setup: countfill + g | W pack | xyc =================
__global__ __launch_bounds__(256) void k_setup(MA A){
    int b = blockIdx.x;
    if(b < 256){
        int e = b*256 + threadIdx.x;
        int rv = A.recv[e];
        unsigned pos = atomicAdd(&A.curs[rv], 1u);
        if(pos < 32u) A.csr[(unsigned)rv*32u + pos] = ((unsigned)e << 14) | (unsigned)A.send[e];
        float r0 = A.rel[e*3+0], r1 = A.rel[e*3+1], r2 = A.rel[e*3+2];
        float av = A.a[e];
        for(int c=0;c<4;c++){
            const float* P = A.P[c];
            float lg[16]; float mx = -1e30f;
            #pragma unroll
            for(int k=0;k<16;k++){
                float v = r0*P[k] + r1*P[16+k] + r2*P[32+k];
                lg[k] = v; mx = fmaxf(mx, v);
            }
            float ssum = 0.f;
            #pragma unroll
            for(int k=0;k<16;k++){ lg[k] = __expf(lg[k]-mx); ssum += lg[k]; }
            float inv = av/ssum;
            float* go = A.g + ((size_t)c*NE + e)*16;
            #pragma unroll
            for(int j=0;j<4;j++){
                ((float4*)go)[j] = make_float4(lg[j*4]*inv, lg[j*4+1]*inv,
                                               lg[j*4+2]*inv, lg[j*4+3]*inv);
            }
        }
        return;
    }
    if(b < 336){
        int t = (b-256)*256 + threadIdx.x;
        const float* W; int Cout; int base; int tl;
        if(t < 8192)      { W=A.W[0]; Cout=64; base=0;     tl=t; }
        else if(t < 12288){ W=A.W[1]; Cout=32; base=8192;  tl=t-8192; }
        else if(t < 16384){ W=A.W[2]; Cout=64; base=12288; tl=t-12288; }
        else              { W=A.W[3]; Cout=32; base=16384; tl=t-16384; }
        int l  = tl & 63;
        int NCT = Cout >> 4;
        int ct = (tl >> 6) % NCT;
        int ks = (tl >> 6) / NCT;
        int col = ct*16 + (l & 15);
        int k0  = ks*32 + ((l >> 4) & 3)*8;
        short8 v;
        #pragma unroll
        for(int j=0;j<8;j++){
            bf16 h = f2b(W[(size_t)(k0+j)*Cout + col]);
            v[j] = (short)*(unsigned short*)&h;
        }
        ((short8*)A.Bp)[base + tl] = v;
        return;
    }
    // xyc[n][64] bf16 = [x[n] | y[n]]
    int t = (b-336)*256 + threadIdx.x;   // [0, 32768)
    int n = t >> 1, half = t & 1;
    const float* src = half ? (A.y + n*32) : (A.x + n*32);
    bf16* dst = A.xyc + (size_t)n*64 + half*32;
    #pragma unroll
    for(int j=0;j<4;j++){
        float4 v0 = ((const float4*)src)[2*j];
        float4 v1 = ((const float4*)src)[2*j+1];
        short8 o; bf16 h;
        h = f2b(v0.x); o[0]=(short)*(unsigned short*)&h;
        h = f2b(v0.y); o[1]=(short)*(unsigned short*)&h;
        h = f2b(v0.z); o[2]=(short)*(unsigned short*)&h;
        h = f2b(v0.w); o[3]=(short)*(unsigned short*)&h;
        h = f2b(v1.x); o[4]=(short)*(unsigned short*)&h;
        h = f2b(v1.y); o[5]=(short)*(unsigned short*)&h;
        h = f2b(v1.z); o[6]=(short)*(unsigned short*)&h;
        h = f2b(v1.w); o[7]=(short)*(unsigned short*)&h;
        ((short8*)dst)[j] = o;
    }
}

// ================= conv phase (persistent): agg -> LDS -> MFMA -> epilogue ==
// COHIN: input via coherent uint loads (2 bf16/uint). F32OUT: final f32 store.
// Else: coherent packed-bf16 store (lane-pair shfl pack).
template<int CIN, int NCT, int MODE, bool COHIN, bool F32OUT>
__device__ __forceinline__ void convp(
    char* sT, const void* fin,
    const float* g, const unsigned* csr, const unsigned* curs,
    const bf16* Bp, const float* bias,
    const float* bns, const float* bno,
    const float* bnm, const float* bnv,
    const float* x, const float* y, void* outv)
{
    constexpr int KD   = CIN*16;
    constexpr int ROWB = KD*2;
    int wv = threadIdx.x >> 6, lane = threadIdx.x & 63;
    const int i     = (CIN==64) ? lane : (lane & 31);
    const int kbase = (CIN==64) ? 0 : ((lane >> 5) * 8);
    constexpr int KPL = (CIN==64) ? 16 : 8;

    for(int tile=0; tile<2; tile++){
        int nbase = (tile*NB + blockIdx.x)*16;
        int node  = nbase + wv;

        // ---------- aggregation (one node per wave) ----------
        const unsigned* crow = csr + (unsigned)node*32u;
        unsigned cnt = curs[node]; if(cnt > 32u) cnt = 32u;
        uint4 c0 = ((const uint4*)crow)[0];
        uint4 c1 = ((const uint4*)crow)[1];
        unsigned uu[8] = {c0.x,c0.y,c0.z,c0.w, c1.x,c1.y,c1.z,c1.w};

        float acc[KPL];
        #pragma unroll
        for(int r=0;r<KPL;r++) acc[r] = 0.f;

        auto edge = [&](unsigned u){
            int sid = (int)(u & 16383u);
            int eid = (int)(u >> 14);
            float fe;
            if(COHIN){
                const unsigned* hu = (const unsigned*)fin;
                unsigned w = cohLoadU32(&hu[(size_t)sid*(CIN/2) + (i>>1)]);
                unsigned w16 = (i & 1) ? (w >> 16) : (w & 0xffffu);
                fe = __uint_as_float(w16 << 16);
            } else {
                fe = b2f(((const bf16*)fin)[sid*CIN + i]);
            }
            const float4* gp = (const float4*)&g[(size_t)eid*16 + kbase];
            if(CIN==64){
                float4 g0=gp[0], g1=gp[1], g2=gp[2], g3=gp[3];
                acc[0]  += g0.x*fe; acc[1]  += g0.y*fe; acc[2]  += g0.z*fe; acc[3]  += g0.w*fe;
                acc[4]  += g1.x*fe; acc[5]  += g1.y*fe; acc[6]  += g1.z*fe; acc[7]  += g1.w*fe;
                acc[8]  += g2.x*fe; acc[9]  += g2.y*fe; acc[10] += g2.z*fe; acc[11] += g2.w*fe;
                acc[12] += g3.x*fe; acc[13] += g3.y*fe; acc[14] += g3.z*fe; acc[15] += g3.w*fe;
            } else {
                float4 g0=gp[0], g1=gp[1];
                acc[0] += g0.x*fe; acc[1] += g0.y*fe; acc[2] += g0.z*fe; acc[3] += g0.w*fe;
                acc[4] += g1.x*fe; acc[5] += g1.y*fe; acc[6] += g1.z*fe; acc[7] += g1.w*fe;
            }
        };
        #pragma unroll
        for(int j=0;j<8;j++){
            if((unsigned)j < cnt) edge(uu[j]);
        }
        for(unsigned j=8; j<cnt; j++) edge(crow[j]);

        // ---------- LDS write (swizzled) ----------
        unsigned xo_ = (unsigned)((wv & 7) << 4);
        if(CIN==64){
            #pragma unroll
            for(int k=0;k<16;k++){
                unsigned byte = (unsigned)wv*ROWB + ((((unsigned)(k*64 + lane))*2u) ^ xo_);
                *(bf16*)(sT + byte) = f2b(acc[k]);
            }
        } else {
            #pragma unroll
            for(int r=0;r<8;r++){
                unsigned byte = (unsigned)wv*ROWB + ((((unsigned)((kbase+r)*32 + i))*2u) ^ xo_);
                *(bf16*)(sT + byte) = f2b(acc[r]);
            }
        }
        __syncthreads();

        // ---------- GEMM + epilogue (waves 0..NCT-1) ----------
        if(wv < NCT){
            int r = lane & 15, h = lane >> 4;
            int c = wv;
            const short8* Bp8 = (const short8*)Bp;
            f32x4 acc4 = (f32x4){0.f,0.f,0.f,0.f};
            unsigned xr = (unsigned)((r & 7) << 4);
            #pragma unroll 8
            for(int ks=0; ks<KD/32; ks++){
                unsigned ab = (unsigned)r*ROWB + (((unsigned)(ks*64 + h*16)) ^ xr);
                short8 af  = *(const short8*)(sT + ab);
                short8 bfr = Bp8[(ks*NCT + c)*64 + lane];
                acc4 = __builtin_amdgcn_mfma_f32_16x16x32_bf16(af, bfr, acc4, 0, 0, 0);
            }
            const int Cout = NCT*16;
            int col = c*16 + r;
            float inv = rsqrtf(bnv[col] + 1e-5f);
            float al  = bns[col] * inv;
            float be  = al*(bias[col] - bnm[col]) + bno[col];
            #pragma unroll
            for(int j=0;j<4;j++){
                int rr = nbase + h*4 + j;
                float v = al*acc4[j] + be;
                float res;
                if(MODE==0){
                    res = fmaxf(v, 0.f);
                } else {
                    float wei = 1.f/(1.f + __expf(-v));
                    res = 2.f*x[rr*32 + col]*wei + 2.f*y[rr*32 + col]*(1.f - wei);
                }
                if(F32OUT){
                    ((float*)outv)[(size_t)rr*32 + col] = res;
                } else {
                    unsigned mine  = bfbits(res);
                    unsigned other = (unsigned)__shfl_xor((int)mine, 1, 64);
                    if((lane & 1) == 0){
                        cohStoreU32((unsigned*)outv + (size_t)rr*(Cout/2) + (col>>1),
                                    mine | (other << 16));
                    }
                }
            }
        }
        __syncthreads();
    }
}

// ---------------- persistent 4-conv kernel (3 fenceless barriers) ----------
__global__ __launch_bounds__(1024, 8) void k_conv4x(MA A){
    __shared__ __align__(16) char sT[32768];
    convp<64,4,0,false,false>(sT, A.xyc, A.g,                  A.csr, A.curs,
        A.Bp,                  A.bb[0],A.bs[0],A.bo[0],A.bm[0],A.bv[0], nullptr,nullptr, A.h1u);
    lightbar(A.bar);
    convp<64,2,1,true ,false>(sT, A.h1u, A.g + (size_t)1*NE*16, A.csr, A.curs,
        A.Bp + (size_t)8192*8, A.bb[1],A.bs[1],A.bo[1],A.bm[1],A.bv[1], A.x,A.y, A.xou);
    lightbar(A.bar);
    convp<32,4,0,true ,false>(sT, A.xou, A.g + (size_t)2*NE*16, A.csr, A.curs,
        A.Bp + (size_t)12288*8,A.bb[2],A.bs[2],A.bo[2],A.bm[2],A.bv[2], nullptr,nullptr, A.h3u);
    lightbar(A.bar);
    convp<64,2,1,true ,true >(sT, A.h3u, A.g + (size_t)3*NE*16, A.csr, A.curs,
        A.Bp + (size_t)16384*8,A.bb[3],A.bs[3],A.bo[3],A.bm[3],A.bv[3], A.x,A.y, A.outp);
}

// ---------------- launch ----------------
extern "C" void kernel_launch(void* const* d_in, const int* in_sizes, int n_in,
                              void* d_out, int out_size, void* d_ws, size_t ws_size,
                              hipStream_t stream){
    MA A;
    A.x    = (const float*)d_in[0];
    A.y    = (const float*)d_in[1];
    A.send = (const int*)d_in[2];
    A.recv = (const int*)d_in[3];
    A.rel  = (const float*)d_in[4];
    A.a    = (const float*)d_in[5];
    for(int i=0;i<4;i++){
        int base = 6 + i*7;
        A.W[i]  = (const float*)d_in[base+0];
        A.P[i]  = (const float*)d_in[base+1];
        A.bb[i] = (const float*)d_in[base+2];
        A.bs[i] = (const float*)d_in[base+3];
        A.bo[i] = (const float*)d_in[base+4];
        A.bm[i] = (const float*)d_in[base+5];
        A.bv[i] = (const float*)d_in[base+6];
    }
    char* w = (char*)d_ws;
    A.g    = (float*)(w);                      // 16,777,216
    A.curs = (unsigned*)(w + 16777216);        //     65,536
    A.bar  = (unsigned*)(w + 16842752);        //      8,192
    A.csr  = (unsigned*)(w + 16850944);        //  2,097,152
    A.h1u  = (unsigned*)(w + 18948096);        //  2,097,152
    A.xou  = (unsigned*)(w + 21045248);        //  1,048,576
    A.h3u  = (unsigned*)(w + 22093824);        //  2,097,152
    A.Bp   = (bf16*)(w + 24190976);            //    327,680
    A.xyc  = (bf16*)(w + 24518656);            //  2,097,152
    A.outp = (float*)d_out;

    // zero curs + barrier state
    hipMemsetAsync(w + 16777216, 0, 65536 + 8192, stream);
    k_setup <<<464, 256, 0, stream>>>(A);
    k_conv4x<<<NB, 1024, 0, stream>>>(A);
}